// Round 13
// baseline (90.939 us; speedup 1.0000x reference)
//
#include <hip/hip_runtime.h>
#include <math.h>

// Chamfer distance via MFMA on MI355X (gfx950).
// B=8, N=M=8192, fp32 in/out. out = concat(dist1[B*N], dist2[B*M]).
//
// d(q,c) = |q|^2 + (|c|^2 - 2 q.c). The parenthesized part is a K<=16 dot
// product on v_mfma_f32_32x32x16_bf16 with split-bf16 (hi+lo) operands; all
// four cross terms kept, plus |c|^2 embedded hi/lo against 1.0. bf16 x bf16
// products are exact in the f32 accumulator.
//
// Round 13 (last structural corner: 8-MFMA bursts / ILP-not-TLP):
// Seven probes (waves 2->8, convoy removal, VMEM halving, liveness
// rotation/pin/fence/contract, prefetch depth 2/4) all left the main
// kernel at ~100k cyc/SIMD vs its 33k matrix floor. R7's absolutes say
// MFMAs run at throughput when they run (MfmaUtil cyc == predicted), loads
// are covered (depth-4 neutral), waves don't help (occupancy neutral).
// Surviving model: MFMA result->VALU latency (~200+ cyc, never isolated
// on gfx950) exposed at red16, ~96-128 cyc after issue in 4-MFMA bodies.
// This version: each wave holds EIGHT query B-frags (QPW=256); per 1 KB
// fragment load it issues 8 back-to-back MFMAs (256 cyc matrix burst),
// then 8 red16s -> first consumption ~224 cyc after issue. 512 blocks
// (2 waves/SIMD, ~250 regs each, fits) interleave one wave's VALU tail
// under the other's burst. Pre-committed: if this is ALSO neutral, the
// wall is structure-invariant and next round documents the ceiling.
//
// NOTE (profiling): the ~40.5 us __amd_rocclr_fillBufferAligned dispatch is
// the harness's 256 MiB workspace poison, fixed per-iteration overhead.

typedef __attribute__((ext_vector_type(8))) short short8;
typedef __attribute__((ext_vector_type(16))) float f32x16;

#define NSPLIT 4                 // candidate slices per (z) scan
#define QPW    256               // queries per wave (8 B-fragments)
#define QPB    (QPW * 4)         // queries per block (4 waves)

__host__ __device__ static inline size_t pad512(size_t x) {
  return (x + 511) & ~(size_t)511;
}

__device__ __forceinline__ unsigned short bf16h(float x) {
  unsigned u = __float_as_uint(x);
  return (unsigned short)((u + 0x7fffu + ((u >> 16) & 1u)) >> 16);  // RNE
}
__device__ __forceinline__ float bf16f(unsigned short h) {
  return __uint_as_float((unsigned)h << 16);
}
__device__ __forceinline__ float m3(float a, float b, float c) {
  return fminf(fminf(a, b), c);  // backend min3 pattern
}
__device__ __forceinline__ float red16(const f32x16& d, float mm) {
  float r0 = m3(d[0], d[1], d[2]);
  float r1 = m3(d[3], d[4], d[5]);
  float r2 = m3(d[6], d[7], d[8]);
  float r3 = m3(d[9], d[10], d[11]);
  float r4 = m3(d[12], d[13], d[14]);
  return m3(m3(r0, r1, r2), m3(r3, r4, d[15]), mm);
}

// ---------------------------------------------------------------------------
// Kernel 1: transform candidate points into A-fragment layout, and
// initialize this z's output region to huge (so uint atomicMin of
// non-negative distances always wins). Per candidate j (group g=j>>5,
// row r=j&31), two 16B fragments:
//   khalf0: [Eh.x,Eh.y,Eh.z, El.x,El.y,El.z, Eh.x,Eh.y]
//   khalf1: [Eh.z, El.x,El.y,El.z, sqh, sql, 0, 0]       (E = -2c, sq = |c|^2)
// stored at frag16[g*64 + h*32 + r] == consumer byte addr g*1024 + lane*16
// with lane = h*32 + r.
// ---------------------------------------------------------------------------
__global__ __launch_bounds__(256) void frag_kernel(
    const float* __restrict__ xyz1, const float* __restrict__ xyz2,
    char* __restrict__ frags, float* __restrict__ out, int B, int N, int M)
{
  const int z = blockIdx.z, dir = z / B, b = z % B;
  const size_t Mpad = pad512((size_t)M), Npad = pad512((size_t)N);
  const float* cp; char* reg_; int Nc; size_t Pc; float* oreg; int NqO;
  if (dir == 0) {  // candidates = xyz2; this z's queries = xyz1 -> dist1[b]
    cp = xyz2 + (size_t)b * M * 3;
    reg_ = frags + (size_t)b * Mpad * 32;
    Nc = M; Pc = Mpad;
    oreg = out + (size_t)b * N; NqO = N;
  } else {         // candidates = xyz1; this z's queries = xyz2 -> dist2[b]
    cp = xyz1 + (size_t)b * N * 3;
    reg_ = frags + (size_t)B * Mpad * 32 + (size_t)b * Npad * 32;
    Nc = N; Pc = Npad;
    oreg = out + (size_t)B * N + (size_t)b * M; NqO = M;
  }
  const size_t j = (size_t)blockIdx.x * 256 + threadIdx.x;

  // output init (N==M==8192 here, so Pc covers NqO; guard anyway)
  if (j < (size_t)NqO) ((unsigned*)oreg)[j] = 0x7f7f7f7fu;
  if (j >= Pc) return;

  float x = 0.f, y = 0.f, zz = 0.f, sq = 3.0e38f;   // pad -> "infinitely far"
  if (j < (size_t)Nc) {
    x = cp[3 * j + 0]; y = cp[3 * j + 1]; zz = cp[3 * j + 2];
    sq = x * x; sq = fmaf(y, y, sq); sq = fmaf(zz, zz, sq);
  }
  const float ex = -2.f * x, ey = -2.f * y, ez = -2.f * zz;
  const unsigned short ehx = bf16h(ex); const unsigned short elx = bf16h(ex - bf16f(ehx));
  const unsigned short ehy = bf16h(ey); const unsigned short ely = bf16h(ey - bf16f(ehy));
  const unsigned short ehz = bf16h(ez); const unsigned short elz = bf16h(ez - bf16f(ehz));
  const unsigned short sh  = bf16h(sq); const unsigned short sl  = bf16h(sq - bf16f(sh));

  short8 f0, f1;
  f0[0] = (short)ehx; f0[1] = (short)ehy; f0[2] = (short)ehz; f0[3] = (short)elx;
  f0[4] = (short)ely; f0[5] = (short)elz; f0[6] = (short)ehx; f0[7] = (short)ehy;
  f1[0] = (short)ehz; f1[1] = (short)elx; f1[2] = (short)ely; f1[3] = (short)elz;
  f1[4] = (short)sh;  f1[5] = (short)sl;  f1[6] = 0;          f1[7] = 0;

  short8* fp = (short8*)reg_ + ((j >> 5) * 64 + (j & 31));
  fp[0]  = f0;    // khalf 0
  fp[32] = f1;    // khalf 1
}

// Query B-fragment (pairs slot-for-slot with the candidate fragment):
//   khalf0: [Qh.x,Qh.y,Qh.z, Qh.x,Qh.y,Qh.z, Ql.x,Ql.y]
//   khalf1: [Ql.z, Ql.x,Ql.y,Ql.z, 1.0, 1.0, 0, 0]
// Slot products sum to  q.(-2c) + |c|^2  exactly as packed.
__device__ __forceinline__ short8 make_qfrag(float x, float y, float z, int hi) {
  const unsigned short hx = bf16h(x); const unsigned short lx = bf16h(x - bf16f(hx));
  const unsigned short hy = bf16h(y); const unsigned short ly = bf16h(y - bf16f(hy));
  const unsigned short hz = bf16h(z); const unsigned short lz = bf16h(z - bf16f(hz));
  const unsigned short ONE = 0x3F80;
  short8 f;
  if (hi == 0) {
    f[0] = (short)hx; f[1] = (short)hy; f[2] = (short)hz; f[3] = (short)hx;
    f[4] = (short)hy; f[5] = (short)hz; f[6] = (short)lx; f[7] = (short)ly;
  } else {
    f[0] = (short)lz; f[1] = (short)lx; f[2] = (short)ly; f[3] = (short)lz;
    f[4] = (short)ONE; f[5] = (short)ONE; f[6] = 0; f[7] = 0;
  }
  return f;
}

// One 32-candidate group: EIGHT builtin MFMAs issued back-to-back (256 cyc
// matrix burst; first result consumed ~224 cyc after issue), then the
// depth-2 prefetch load, then 8 red16s (VALU tail overlaps the partner
// wave's burst).
#define GROUP_BODY(fcur, gofs)                                                \
  {                                                                           \
    f32x16 d0 = __builtin_amdgcn_mfma_f32_32x32x16_bf16(fcur, bq0, zacc, 0, 0, 0); \
    f32x16 d1 = __builtin_amdgcn_mfma_f32_32x32x16_bf16(fcur, bq1, zacc, 0, 0, 0); \
    f32x16 d2 = __builtin_amdgcn_mfma_f32_32x32x16_bf16(fcur, bq2, zacc, 0, 0, 0); \
    f32x16 d3 = __builtin_amdgcn_mfma_f32_32x32x16_bf16(fcur, bq3, zacc, 0, 0, 0); \
    f32x16 d4 = __builtin_amdgcn_mfma_f32_32x32x16_bf16(fcur, bq4, zacc, 0, 0, 0); \
    f32x16 d5 = __builtin_amdgcn_mfma_f32_32x32x16_bf16(fcur, bq5, zacc, 0, 0, 0); \
    f32x16 d6 = __builtin_amdgcn_mfma_f32_32x32x16_bf16(fcur, bq6, zacc, 0, 0, 0); \
    f32x16 d7 = __builtin_amdgcn_mfma_f32_32x32x16_bf16(fcur, bq7, zacc, 0, 0, 0); \
    fcur = *(const short8*)(gp + (size_t)(gofs) * 1024);                      \
    mm0 = red16(d0, mm0);                                                     \
    mm1 = red16(d1, mm1);                                                     \
    mm2 = red16(d2, mm2);                                                     \
    mm3 = red16(d3, mm3);                                                     \
    mm4 = red16(d4, mm4);                                                     \
    mm5 = red16(d5, mm5);                                                     \
    mm6 = red16(d6, mm6);                                                     \
    mm7 = red16(d7, mm7);                                                     \
  }

// ---------------------------------------------------------------------------
// Kernel 2: 256 threads (4 waves), no LDS, no barriers. Each wave owns 256
// queries (8 B-frags) and streams its candidate slice global->register
// with a depth-2 rotating prefetch. Per group: 1 global_load_dwordx4 ->
// 8 MFMA burst -> 8 red16. 512 blocks = 2 waves/SIMD; the two waves
// interleave burst/tail. Partial minima merge via uint atomicMin.
// Grid is 1D with id%(2B)==z so same-z blocks share an XCD's L2.
// ---------------------------------------------------------------------------
__global__ __launch_bounds__(256, 2) void chamfer_mfma(
    const float* __restrict__ xyz1, const float* __restrict__ xyz2,
    const char* __restrict__ frags, float* __restrict__ out,
    int B, int N, int M)
{
  const int id   = (int)blockIdx.x;
  const int z    = id % (2 * B);          // fastest -> XCD (%8) keyed by z
  const int rest = id / (2 * B);
  const int by   = rest % NSPLIT;
  const int bx   = rest / NSPLIT;

  const int dir = z / B, b = z % B;
  const size_t Mpad = pad512((size_t)M), Npad = pad512((size_t)N);
  const float* qp; float* o; const char* fr; int Nq, Nc;
  if (dir == 0) {   // queries = xyz1, candidates = xyz2
    qp = xyz1 + (size_t)b * N * 3;
    o  = out + (size_t)b * N;
    fr = frags + (size_t)b * Mpad * 32;
    Nq = N; Nc = (int)Mpad;
  } else {          // queries = xyz2, candidates = xyz1
    qp = xyz2 + (size_t)b * M * 3;
    o  = out + (size_t)B * N + (size_t)b * M;
    fr = frags + (size_t)B * Mpad * 32 + (size_t)b * Npad * 32;
    Nq = M; Nc = (int)Npad;
  }
  if (bx * QPB >= Nq) return;   // block-uniform early out

  const int lane = threadIdx.x & 63;
  const int wid  = threadIdx.x >> 6;
  const int hi   = lane >> 5;

  // ---- candidate slice: gq groups of 32 (Nc multiple of 512 -> gq even) ----
  const int gq = Nc / (32 * NSPLIT);
  const char* gp = fr + (size_t)by * gq * 1024 + (size_t)lane * 16;

  // ---- eight query sets per wave ----
  const int qbase = bx * QPB + wid * QPW;
  int nn[8]; float sqq[8]; short8 bq[8];
#pragma unroll
  for (int k = 0; k < 8; ++k) {
    const int n = qbase + (lane & 31) + 32 * k;
    nn[k] = n;
    const int nc = n < Nq ? n : Nq - 1;
    const float qx = qp[3 * nc], qy = qp[3 * nc + 1], qz = qp[3 * nc + 2];
    float s = qx * qx; s = fmaf(qy, qy, s); s = fmaf(qz, qz, s);
    sqq[k] = s;
    bq[k] = make_qfrag(qx, qy, qz, hi);
  }
  const short8 bq0 = bq[0], bq1 = bq[1], bq2 = bq[2], bq3 = bq[3];
  const short8 bq4 = bq[4], bq5 = bq[5], bq6 = bq[6], bq7 = bq[7];

  const f32x16 zacc = {0.f,0.f,0.f,0.f,0.f,0.f,0.f,0.f,
                       0.f,0.f,0.f,0.f,0.f,0.f,0.f,0.f};
  float mm0 = 3.0e38f, mm1 = 3.0e38f, mm2 = 3.0e38f, mm3 = 3.0e38f;
  float mm4 = 3.0e38f, mm5 = 3.0e38f, mm6 = 3.0e38f, mm7 = 3.0e38f;

  // depth-2 rotating prefetch. In-loop loads may run up to 2 KB past the
  // slice (and, for the last slice of the last region, past the 4 MB frag
  // area) — values are never consumed and the workspace is >=256 MB.
  short8 f0 = *(const short8*)(gp);
  short8 f1 = *(const short8*)(gp + 1024);
#pragma unroll 1
  for (int g = 0; g < gq; g += 2) {
    GROUP_BODY(f0, g + 2)
    GROUP_BODY(f1, g + 3)
  }

  // C layout (m74/m101): col = lane&31 (query), rows split across lane^32.
  float mm[8] = {mm0, mm1, mm2, mm3, mm4, mm5, mm6, mm7};
#pragma unroll
  for (int k = 0; k < 8; ++k) {
    float v = fminf(mm[k], __shfl_xor(mm[k], 32));
    if (lane < 32 && nn[k] < Nq)
      atomicMin((unsigned int*)(o + nn[k]), __float_as_uint(fmaxf(v + sqq[k], 0.f)));
  }
}

extern "C" void kernel_launch(void* const* d_in, const int* in_sizes, int n_in,
                              void* d_out, int out_size, void* d_ws, size_t ws_size,
                              hipStream_t stream) {
  const float* xyz1 = (const float*)d_in[0];
  const float* xyz2 = (const float*)d_in[1];
  float* out = (float*)d_out;

  const int B = 8;                      // fixed by the reference problem
  const int N = in_sizes[0] / (B * 3);  // 8192
  const int M = in_sizes[1] / (B * 3);  // 8192

  const size_t Npad = pad512((size_t)N), Mpad = pad512((size_t)M);
  char* frags = (char*)d_ws;            // needs B*(Npad+Mpad)*32 = 4 MB here

  const size_t pmax = Npad > Mpad ? Npad : Mpad;
  dim3 g1((unsigned)(pmax / 256), 1, 2 * B);
  frag_kernel<<<g1, dim3(256), 0, stream>>>(xyz1, xyz2, frags, out, B, N, M);

  const int nmax = N > M ? N : M;
  const unsigned nx = (unsigned)((nmax + QPB - 1) / QPB);
  dim3 g2(nx * NSPLIT * 2 * B, 1, 1);   // id%(2B)==z -> same-z blocks share XCD
  chamfer_mfma<<<g2, dim3(256), 0, stream>>>(xyz1, xyz2, frags, out, B, N, M);
}

// Round 14
// 88.957 us; speedup vs baseline: 1.0223x; 1.0223x over previous
//
#include <hip/hip_runtime.h>
#include <math.h>

// Chamfer distance via MFMA on MI355X (gfx950) — FINAL (locked at R6 config).
// B=8, N=M=8192, fp32 in/out. out = concat(dist1[B*N], dist2[B*M]).
//
// d(q,c) = |q|^2 + (|c|^2 - 2 q.c). The parenthesized part is a K<=16 dot
// product on v_mfma_f32_32x32x16_bf16 with split-bf16 (hi+lo) operands; all
// four cross terms kept, plus |c|^2 embedded hi/lo against 1.0. bf16 x bf16
// products are exact in the f32 accumulator. 130.7 us (VALU scalar scan)
// -> 88.8 us via MFMA + streaming structure.
//
// SESSION LEDGER (why this is the stopping point):
//  - Matrix-pipe floor: 1.048e6 mfma_32x32x16 x 8.07 cyc/CU = 13.8 us.
//    Measured MfmaUtil x dur = 13.9-14.3 us EVERY round: MFMAs run at full
//    rate when they run.
//  - VALU: VALUBusy x dur = 17.0-17.5 us every round (~2.5x the 8-min3/MFMA
//    floor; surplus consistent with AGPR-operand copies, unprovable blind).
//  - dur(main) ~= MFMA + VALU + ~12 us serial, invariant across 8 structural
//    axes: occupancy 1.5->8 waves/SIMD, LDS-convoy removal, VMEM 512->137MB,
//    prefetch depth 2/4, liveness rotation/pin/sched_barrier/launch-bounds
//    contract, MFMA burst 2/4/8. The pipes never overlap cross-wave.
//  - Instruction-level escapes are correctness-broken on this toolchain:
//    asm MFMA (R8) and asm consumers of MFMA results (R10) both silently
//    corrupt (hazard recognizer skips asm blocks).
//  - Harness floor: 40.6 us workspace-poison fill (256 MiB @ 83% HBM peak,
//    per-iteration, not ours) + ~4 us frag + ~42 us main + gaps ~= 89 us.
//
// Kernel 1 pre-transforms candidates into MFMA A-fragment order (4 MB in
// d_ws) and initializes outputs; kernel 2 streams fragments global->reg
// (L2-resident; id%16 z->XCD mapping keeps each XCD's 512 KB slice in its
// private L2), 4 MFMA + 4 rotated red16 per 1 KB fragment, atomicMin merge.

typedef __attribute__((ext_vector_type(8))) short short8;
typedef __attribute__((ext_vector_type(16))) float f32x16;

#define NSPLIT 4                 // candidate quarters per (z) scan
#define QPW    128               // queries per wave (4 B-fragments)
#define QPB    (QPW * 4)         // queries per block (4 waves)

__host__ __device__ static inline size_t pad512(size_t x) {
  return (x + 511) & ~(size_t)511;
}

__device__ __forceinline__ unsigned short bf16h(float x) {
  unsigned u = __float_as_uint(x);
  return (unsigned short)((u + 0x7fffu + ((u >> 16) & 1u)) >> 16);  // RNE
}
__device__ __forceinline__ float bf16f(unsigned short h) {
  return __uint_as_float((unsigned)h << 16);
}
__device__ __forceinline__ float m3(float a, float b, float c) {
  return fminf(fminf(a, b), c);  // backend min3 pattern
}
__device__ __forceinline__ float red16(const f32x16& d, float mm) {
  float r0 = m3(d[0], d[1], d[2]);
  float r1 = m3(d[3], d[4], d[5]);
  float r2 = m3(d[6], d[7], d[8]);
  float r3 = m3(d[9], d[10], d[11]);
  float r4 = m3(d[12], d[13], d[14]);
  return m3(m3(r0, r1, r2), m3(r3, r4, d[15]), mm);
}

// ---------------------------------------------------------------------------
// Kernel 1: transform candidate points into A-fragment layout, and
// initialize this z's output region to huge (so uint atomicMin of
// non-negative distances always wins). Per candidate j (group g=j>>5,
// row r=j&31), two 16B fragments:
//   khalf0: [Eh.x,Eh.y,Eh.z, El.x,El.y,El.z, Eh.x,Eh.y]
//   khalf1: [Eh.z, El.x,El.y,El.z, sqh, sql, 0, 0]       (E = -2c, sq = |c|^2)
// stored at frag16[g*64 + h*32 + r] == consumer byte addr g*1024 + lane*16
// with lane = h*32 + r.
// ---------------------------------------------------------------------------
__global__ __launch_bounds__(256) void frag_kernel(
    const float* __restrict__ xyz1, const float* __restrict__ xyz2,
    char* __restrict__ frags, float* __restrict__ out, int B, int N, int M)
{
  const int z = blockIdx.z, dir = z / B, b = z % B;
  const size_t Mpad = pad512((size_t)M), Npad = pad512((size_t)N);
  const float* cp; char* reg_; int Nc; size_t Pc; float* oreg; int NqO;
  if (dir == 0) {  // candidates = xyz2; this z's queries = xyz1 -> dist1[b]
    cp = xyz2 + (size_t)b * M * 3;
    reg_ = frags + (size_t)b * Mpad * 32;
    Nc = M; Pc = Mpad;
    oreg = out + (size_t)b * N; NqO = N;
  } else {         // candidates = xyz1; this z's queries = xyz2 -> dist2[b]
    cp = xyz1 + (size_t)b * N * 3;
    reg_ = frags + (size_t)B * Mpad * 32 + (size_t)b * Npad * 32;
    Nc = N; Pc = Npad;
    oreg = out + (size_t)B * N + (size_t)b * M; NqO = M;
  }
  const size_t j = (size_t)blockIdx.x * 256 + threadIdx.x;

  // output init (N==M==8192 here, so Pc covers NqO; guard anyway)
  if (j < (size_t)NqO) ((unsigned*)oreg)[j] = 0x7f7f7f7fu;
  if (j >= Pc) return;

  float x = 0.f, y = 0.f, zz = 0.f, sq = 3.0e38f;   // pad -> "infinitely far"
  if (j < (size_t)Nc) {
    x = cp[3 * j + 0]; y = cp[3 * j + 1]; zz = cp[3 * j + 2];
    sq = x * x; sq = fmaf(y, y, sq); sq = fmaf(zz, zz, sq);
  }
  const float ex = -2.f * x, ey = -2.f * y, ez = -2.f * zz;
  const unsigned short ehx = bf16h(ex); const unsigned short elx = bf16h(ex - bf16f(ehx));
  const unsigned short ehy = bf16h(ey); const unsigned short ely = bf16h(ey - bf16f(ehy));
  const unsigned short ehz = bf16h(ez); const unsigned short elz = bf16h(ez - bf16f(ehz));
  const unsigned short sh  = bf16h(sq); const unsigned short sl  = bf16h(sq - bf16f(sh));

  short8 f0, f1;
  f0[0] = (short)ehx; f0[1] = (short)ehy; f0[2] = (short)ehz; f0[3] = (short)elx;
  f0[4] = (short)ely; f0[5] = (short)elz; f0[6] = (short)ehx; f0[7] = (short)ehy;
  f1[0] = (short)ehz; f1[1] = (short)elx; f1[2] = (short)ely; f1[3] = (short)elz;
  f1[4] = (short)sh;  f1[5] = (short)sl;  f1[6] = 0;          f1[7] = 0;

  short8* fp = (short8*)reg_ + ((j >> 5) * 64 + (j & 31));
  fp[0]  = f0;    // khalf 0
  fp[32] = f1;    // khalf 1
}

// Query B-fragment (pairs slot-for-slot with the candidate fragment):
//   khalf0: [Qh.x,Qh.y,Qh.z, Qh.x,Qh.y,Qh.z, Ql.x,Ql.y]
//   khalf1: [Ql.z, Ql.x,Ql.y,Ql.z, 1.0, 1.0, 0, 0]
// Slot products sum to  q.(-2c) + |c|^2  exactly as packed.
__device__ __forceinline__ short8 make_qfrag(float x, float y, float z, int hi) {
  const unsigned short hx = bf16h(x); const unsigned short lx = bf16h(x - bf16f(hx));
  const unsigned short hy = bf16h(y); const unsigned short ly = bf16h(y - bf16f(hy));
  const unsigned short hz = bf16h(z); const unsigned short lz = bf16h(z - bf16f(hz));
  const unsigned short ONE = 0x3F80;
  short8 f;
  if (hi == 0) {
    f[0] = (short)hx; f[1] = (short)hy; f[2] = (short)hz; f[3] = (short)hx;
    f[4] = (short)hy; f[5] = (short)hz; f[6] = (short)lx; f[7] = (short)ly;
  } else {
    f[0] = (short)lz; f[1] = (short)lx; f[2] = (short)ly; f[3] = (short)lz;
    f[4] = (short)ONE; f[5] = (short)ONE; f[6] = 0; f[7] = 0;
  }
  return f;
}

// ---------------------------------------------------------------------------
// Kernel 2: 256 threads (4 waves), no LDS, no barriers. Each wave owns 128
// queries (4 B-frags) and streams its candidate quarter global->register
// with depth-2 prefetch. Per A-fragment: 4 MFMA + 4 red16, rotated one step
// so at most TWO f32x16 results are live. Partial minima merge via uint
// atomicMin. Grid is 1D with id%(2B) == z so same-z blocks share an XCD L2.
// ---------------------------------------------------------------------------
__global__ __launch_bounds__(256, 4) void chamfer_mfma(
    const float* __restrict__ xyz1, const float* __restrict__ xyz2,
    const char* __restrict__ frags, float* __restrict__ out,
    int B, int N, int M)
{
  const int id   = (int)blockIdx.x;
  const int z    = id % (2 * B);          // fastest -> XCD (%8) keyed by z
  const int rest = id / (2 * B);
  const int by   = rest % NSPLIT;
  const int bx   = rest / NSPLIT;

  const int dir = z / B, b = z % B;
  const size_t Mpad = pad512((size_t)M), Npad = pad512((size_t)N);
  const float* qp; float* o; const char* fr; int Nq, Nc;
  if (dir == 0) {   // queries = xyz1, candidates = xyz2
    qp = xyz1 + (size_t)b * N * 3;
    o  = out + (size_t)b * N;
    fr = frags + (size_t)b * Mpad * 32;
    Nq = N; Nc = (int)Mpad;
  } else {          // queries = xyz2, candidates = xyz1
    qp = xyz2 + (size_t)b * M * 3;
    o  = out + (size_t)B * N + (size_t)b * M;
    fr = frags + (size_t)B * Mpad * 32 + (size_t)b * Npad * 32;
    Nq = M; Nc = (int)Npad;
  }
  if (bx * QPB >= Nq) return;   // block-uniform early out

  const int lane = threadIdx.x & 63;
  const int wid  = threadIdx.x >> 6;
  const int hi   = lane >> 5;

  // ---- candidate quarter: gq groups of 32 (gq even) ----
  const int gq = Nc / (32 * NSPLIT);
  const char* gp = fr + (size_t)by * gq * 1024 + (size_t)lane * 16;

  // ---- four query sets per wave ----
  const int qbase = bx * QPB + wid * QPW;
  const int n0 = qbase + (lane & 31);
  const int n1 = n0 + 32;
  const int n2 = n0 + 64;
  const int n3 = n0 + 96;
  const int n0c = n0 < Nq ? n0 : Nq - 1;
  const int n1c = n1 < Nq ? n1 : Nq - 1;
  const int n2c = n2 < Nq ? n2 : Nq - 1;
  const int n3c = n3 < Nq ? n3 : Nq - 1;
  const float q0x = qp[3 * n0c], q0y = qp[3 * n0c + 1], q0z = qp[3 * n0c + 2];
  const float q1x = qp[3 * n1c], q1y = qp[3 * n1c + 1], q1z = qp[3 * n1c + 2];
  const float q2x = qp[3 * n2c], q2y = qp[3 * n2c + 1], q2z = qp[3 * n2c + 2];
  const float q3x = qp[3 * n3c], q3y = qp[3 * n3c + 1], q3z = qp[3 * n3c + 2];
  float sqq0 = q0x * q0x; sqq0 = fmaf(q0y, q0y, sqq0); sqq0 = fmaf(q0z, q0z, sqq0);
  float sqq1 = q1x * q1x; sqq1 = fmaf(q1y, q1y, sqq1); sqq1 = fmaf(q1z, q1z, sqq1);
  float sqq2 = q2x * q2x; sqq2 = fmaf(q2y, q2y, sqq2); sqq2 = fmaf(q2z, q2z, sqq2);
  float sqq3 = q3x * q3x; sqq3 = fmaf(q3y, q3y, sqq3); sqq3 = fmaf(q3z, q3z, sqq3);
  const short8 bq0 = make_qfrag(q0x, q0y, q0z, hi);
  const short8 bq1 = make_qfrag(q1x, q1y, q1z, hi);
  const short8 bq2 = make_qfrag(q2x, q2y, q2z, hi);
  const short8 bq3 = make_qfrag(q3x, q3y, q3z, hi);

  const f32x16 zacc = {0.f,0.f,0.f,0.f,0.f,0.f,0.f,0.f,
                       0.f,0.f,0.f,0.f,0.f,0.f,0.f,0.f};
  float mm0 = 3.0e38f, mm1 = 3.0e38f, mm2 = 3.0e38f, mm3 = 3.0e38f;

  // depth-2 register prefetch. Prefetch may run up to 2 KB past the quarter
  // (and, for the last quarter of the last region, past the 4 MB frag
  // area) — values are never consumed and the workspace is >=256 MB.
  short8 f0 = *(const short8*)(gp);
  short8 f1 = *(const short8*)(gp + 1024);
#pragma unroll 1
  for (int g = 0; g < gq; g += 2) {
    const short8 nf0 = *(const short8*)(gp + (size_t)(g + 2) * 1024);
    {
      // rotated: issue MFMA k+1, then reduce result k  (max 2 live f32x16)
      f32x16 d0 = __builtin_amdgcn_mfma_f32_32x32x16_bf16(f0, bq0, zacc, 0, 0, 0);
      f32x16 d1 = __builtin_amdgcn_mfma_f32_32x32x16_bf16(f0, bq1, zacc, 0, 0, 0);
      mm0 = red16(d0, mm0);
      f32x16 d2 = __builtin_amdgcn_mfma_f32_32x32x16_bf16(f0, bq2, zacc, 0, 0, 0);
      mm1 = red16(d1, mm1);
      f32x16 d3 = __builtin_amdgcn_mfma_f32_32x32x16_bf16(f0, bq3, zacc, 0, 0, 0);
      mm2 = red16(d2, mm2);
      mm3 = red16(d3, mm3);
    }
    f0 = nf0;

    const short8 nf1 = *(const short8*)(gp + (size_t)(g + 3) * 1024);
    {
      f32x16 d0 = __builtin_amdgcn_mfma_f32_32x32x16_bf16(f1, bq0, zacc, 0, 0, 0);
      f32x16 d1 = __builtin_amdgcn_mfma_f32_32x32x16_bf16(f1, bq1, zacc, 0, 0, 0);
      mm0 = red16(d0, mm0);
      f32x16 d2 = __builtin_amdgcn_mfma_f32_32x32x16_bf16(f1, bq2, zacc, 0, 0, 0);
      mm1 = red16(d1, mm1);
      f32x16 d3 = __builtin_amdgcn_mfma_f32_32x32x16_bf16(f1, bq3, zacc, 0, 0, 0);
      mm2 = red16(d2, mm2);
      mm3 = red16(d3, mm3);
    }
    f1 = nf1;
  }

  // C layout (m74/m101): col = lane&31 (query), rows split across lane^32.
  mm0 = fminf(mm0, __shfl_xor(mm0, 32));
  mm1 = fminf(mm1, __shfl_xor(mm1, 32));
  mm2 = fminf(mm2, __shfl_xor(mm2, 32));
  mm3 = fminf(mm3, __shfl_xor(mm3, 32));
  if (lane < 32) {
    if (n0 < Nq) atomicMin((unsigned int*)(o + n0), __float_as_uint(fmaxf(mm0 + sqq0, 0.f)));
    if (n1 < Nq) atomicMin((unsigned int*)(o + n1), __float_as_uint(fmaxf(mm1 + sqq1, 0.f)));
    if (n2 < Nq) atomicMin((unsigned int*)(o + n2), __float_as_uint(fmaxf(mm2 + sqq2, 0.f)));
    if (n3 < Nq) atomicMin((unsigned int*)(o + n3), __float_as_uint(fmaxf(mm3 + sqq3, 0.f)));
  }
}

extern "C" void kernel_launch(void* const* d_in, const int* in_sizes, int n_in,
                              void* d_out, int out_size, void* d_ws, size_t ws_size,
                              hipStream_t stream) {
  const float* xyz1 = (const float*)d_in[0];
  const float* xyz2 = (const float*)d_in[1];
  float* out = (float*)d_out;

  const int B = 8;                      // fixed by the reference problem
  const int N = in_sizes[0] / (B * 3);  // 8192
  const int M = in_sizes[1] / (B * 3);  // 8192

  const size_t Npad = pad512((size_t)N), Mpad = pad512((size_t)M);
  char* frags = (char*)d_ws;            // needs B*(Npad+Mpad)*32 = 4 MB here

  const size_t pmax = Npad > Mpad ? Npad : Mpad;
  dim3 g1((unsigned)(pmax / 256), 1, 2 * B);
  frag_kernel<<<g1, dim3(256), 0, stream>>>(xyz1, xyz2, frags, out, B, N, M);

  const int nmax = N > M ? N : M;
  const unsigned nx = (unsigned)((nmax + QPB - 1) / QPB);
  dim3 g2(nx * NSPLIT * 2 * B, 1, 1);   // id%(2B)==z -> same-z blocks share XCD
  chamfer_mfma<<<g2, dim3(256), 0, stream>>>(xyz1, xyz2, frags, out, B, N, M);
}